// Round 7
// baseline (619.560 us; speedup 1.0000x reference)
//
#include <hip/hip_runtime.h>
#include <stdint.h>

#define AS1 __attribute__((address_space(1)))
#define AS3 __attribute__((address_space(3)))

typedef __attribute__((ext_vector_type(8))) short short8;
typedef __attribute__((ext_vector_type(4))) float floatx4;

__device__ __forceinline__ unsigned short f2b_rne(float f) {
  union { float f; unsigned u; } c; c.f = f;
  unsigned u = c.u;
  unsigned r = u + 0x7fffu + ((u >> 16) & 1u);
  return (unsigned short)(r >> 16);
}

// ---------------------------------------------------------------------------
// Weight prep: Wt[n][k] = bf16(W_seg[k][c])  (B^T layout, K contiguous)
// rows 0..255=W_val, 256..511=W_so, 512..767=W_tso.
// rows 768..1023: head-interleaved aw layout — idx=n-768, h=idx>>5, w=idx&31:
// w<16 -> W_aw col h*16+w ; w>=16 -> W_taw col h*16+(w-16). Each head's 32
// joint-softmax logits are one contiguous 32-col group -> 16-lane shfl softmax.
// ---------------------------------------------------------------------------
__global__ void prep_weights(const float* __restrict__ Wv,  const float* __restrict__ bv,
                             const float* __restrict__ Wso, const float* __restrict__ bso,
                             const float* __restrict__ Waw, const float* __restrict__ baw,
                             const float* __restrict__ Wtso,const float* __restrict__ btso,
                             const float* __restrict__ Wtaw,const float* __restrict__ btaw,
                             unsigned short* __restrict__ Wt, float* __restrict__ bcat) {
  int n = blockIdx.x;   // 0..1023
  int k = threadIdx.x;  // 0..255
  const float* W; const float* b; int c, N;
  if (n < 256)      { W = Wv;   b = bv;   c = n;       N = 256; }
  else if (n < 512) { W = Wso;  b = bso;  c = n - 256; N = 256; }
  else if (n < 768) { W = Wtso; b = btso; c = n - 512; N = 256; }
  else {
    int idx = n - 768, h = idx >> 5, w = idx & 31;
    if (w < 16) { W = Waw;  b = baw;  c = h * 16 + w;        N = 128; }
    else        { W = Wtaw; b = btaw; c = h * 16 + (w - 16); N = 128; }
  }
  Wt[n * 256 + k] = f2b_rne(W[(size_t)k * N + c]);
  if (k == 0) bcat[n] = b[c];
}

// ---------------------------------------------------------------------------
// Main GEMM, 128x256 block (512 thr = 8 waves of 64x64), BK=64, grid (4, M/128).
// Doubling N per block vs R6 halves per-output A staging (loads + fp32->bf16
// conversion) and halves A's L2 re-read traffic (4 blocks/panel instead of 8).
// XCD remap (m204 bijective variant, since 3060 % 8 != 0) keeps the 4
// co-panel blocks on ONE XCD so the panel lives in that XCD's L2.
//   nt 0 value | 1 so | 2 tso | 3 aw + fused 16-lane shfl softmax.
// B staged via global_load_lds (linear dest, pre-swizzled source); A staged
// fp32->bf16 via swizzled ds_write; fragment reads 16B-XOR-swizzled (2-way,
// free). All verified in R3/R6 (same swizzle algebra, absmax 0.03125).
// ---------------------------------------------------------------------------
__global__ __launch_bounds__(512, 4)
void gemm_main(const float* __restrict__ Q, const float* __restrict__ X,
               const unsigned short* __restrict__ Wt, const float* __restrict__ bcat,
               float* __restrict__ out, int M) {
  __shared__ __align__(16) unsigned short As[128 * 64];  // 16 KB
  __shared__ __align__(16) unsigned short Bs[256 * 64];  // 32 KB

  // ---- XCD-locality remap, bijective for nwg = 4*gridDim.y (3060) ----
  const int nwg = 4 * gridDim.y;
  const int q = nwg >> 3, r = nwg & 7;
  const int id = blockIdx.x + 4 * blockIdx.y;
  const int c  = id & 7, j = id >> 3;
  const int w  = (c < r ? c * (q + 1) : r * (q + 1) + (c - r) * q) + j;
  const int nt = w & 3;    // 0..3: 256-col super-tile
  const int mt = w >> 2;   // consecutive w share mt -> co-panel blocks same XCD

  const int mBase = mt * 128;
  const float* A = (nt == 0) ? X : Q;

  const int tid  = threadIdx.x;
  const int lane = tid & 63;
  const int wid  = tid >> 6;        // 0..7
  const int wm   = (wid >> 2) * 64; // wave m-offset: 0 or 64
  const int wn   = (wid & 3) * 64;  // wave n-offset within 256: 0/64/128/192
  const int lrow = lane & 15;
  const int quad = lane >> 4;

  floatx4 acc[4][4] = {};

  const float* Ab = A + (size_t)mBase * 256;
  const unsigned short* Bb = Wt + (size_t)nt * 256 * 256;

  for (int s = 0; s < 4; ++s) {
    const int k0 = s * 64;
    __syncthreads();
    // ---- B stage: 256x64 bf16 = 2048 x 16B chunks, 4/thread.
    // LDS dest linear; global source column pre-swizzled (m173 pattern).
#pragma unroll
    for (int jj = 0; jj < 4; ++jj) {
      int ch = jj * 512 + tid;            // 0..2047
      int rB = ch >> 3, kc = ch & 7;
      const unsigned short* g = Bb + (size_t)rB * 256 + k0 + ((kc ^ (rB & 7)) << 3);
      unsigned ldsoff = (unsigned)((jj * 512 + (tid & ~63)) * 16);  // wave-uniform
      __builtin_amdgcn_global_load_lds((const AS1 void*)g,
                                       (AS3 void*)(((char*)Bs) + ldsoff), 16, 0, 0);
    }
    // ---- A stage: 128x64 fp32 -> bf16: 2048 float4 chunks, 4/thread ----
    float4 va[4];
#pragma unroll
    for (int i = 0; i < 4; ++i) {
      int id2 = i * 512 + tid;
      int rA = id2 >> 4, kc4 = id2 & 15;
      va[i] = *(const float4*)(Ab + (size_t)rA * 256 + k0 + kc4 * 4);
    }
#pragma unroll
    for (int i = 0; i < 4; ++i) {
      int id2 = i * 512 + tid;
      int rA = id2 >> 4, kc4 = id2 & 15;
      uint2 pk;
      pk.x = ((unsigned)f2b_rne(va[i].y) << 16) | f2b_rne(va[i].x);
      pk.y = ((unsigned)f2b_rne(va[i].w) << 16) | f2b_rne(va[i].z);
      int idx = rA * 64 + ((((kc4 >> 1) ^ (rA & 7)) << 3) + (kc4 & 1) * 4);
      *(uint2*)&As[idx] = pk;
    }
    __syncthreads();
    // ---- compute: wave does 64x64 = 4x4 of 16x16x32, two k-halves.
    // Fragments loaded per-half (af[4]/bf[4] live, not af[2][4]) to fit
    // the <=128-VGPR budget of launch_bounds(512,4).
#pragma unroll
    for (int t = 0; t < 2; ++t) {
      short8 af[4], bf[4];
#pragma unroll
      for (int mi = 0; mi < 4; ++mi) {
        int row = wm + mi * 16 + lrow;
        af[mi] = *(const short8*)&As[row * 64 + (((t * 4 + quad) ^ (row & 7)) << 3)];
      }
#pragma unroll
      for (int ni = 0; ni < 4; ++ni) {
        int row = wn + ni * 16 + lrow;
        bf[ni] = *(const short8*)&Bs[row * 64 + (((t * 4 + quad) ^ (row & 7)) << 3)];
      }
#pragma unroll
      for (int mi = 0; mi < 4; ++mi)
#pragma unroll
        for (int ni = 0; ni < 4; ++ni)
          acc[mi][ni] = __builtin_amdgcn_mfma_f32_16x16x32_bf16(af[mi], bf[ni], acc[mi][ni], 0, 0, 0);
    }
  }

  // C/D layout: col = lane&15, row = quad*4 + reg (m89-verified)
  if (nt < 3) {
    float* Oseg = out + (size_t)nt * ((size_t)M * 256);
#pragma unroll
    for (int ni = 0; ni < 4; ++ni) {
      float bias = bcat[nt * 256 + wn + ni * 16 + lrow];
#pragma unroll
      for (int mi = 0; mi < 4; ++mi) {
#pragma unroll
        for (int r2 = 0; r2 < 4; ++r2) {
          int row = mBase + wm + mi * 16 + quad * 4 + r2;
          int col = wn + ni * 16 + lrow;
          Oseg[(size_t)row * 256 + col] = acc[mi][ni][r2] + bias;
        }
      }
    }
  } else {
    // ---- aw: joint softmax over 32 logits per (row, head); wave = 2 heads.
    float* awc = out + (size_t)3 * ((size_t)M * 256);
    float* awt = awc + (size_t)M * 128;
    float bias[4];
#pragma unroll
    for (int ni = 0; ni < 4; ++ni) bias[ni] = bcat[768 + wn + ni * 16 + lrow];
    const int hbase = (wn >> 5);   // 2 heads per wave (32 cols each)
#pragma unroll
    for (int mi = 0; mi < 4; ++mi) {
#pragma unroll
      for (int r2 = 0; r2 < 4; ++r2) {
        const int row = mBase + wm + mi * 16 + quad * 4 + r2;
#pragma unroll
        for (int hg = 0; hg < 2; ++hg) {
          float a = acc[mi][2 * hg + 0][r2] + bias[2 * hg + 0];   // caw logit
          float b = acc[mi][2 * hg + 1][r2] + bias[2 * hg + 1];   // taw logit
          float mx = fmaxf(a, b);
          mx = fmaxf(mx, __shfl_xor(mx, 1));
          mx = fmaxf(mx, __shfl_xor(mx, 2));
          mx = fmaxf(mx, __shfl_xor(mx, 4));
          mx = fmaxf(mx, __shfl_xor(mx, 8));
          float ea = __expf(a - mx), eb = __expf(b - mx);
          float ssum = ea + eb;
          ssum += __shfl_xor(ssum, 1);
          ssum += __shfl_xor(ssum, 2);
          ssum += __shfl_xor(ssum, 4);
          ssum += __shfl_xor(ssum, 8);
          float inv = 1.0f / ssum;
          const int h = hbase + hg;
          awc[(size_t)row * 128 + h * 16 + lrow] = ea * inv;
          awt[(size_t)row * 128 + h * 16 + lrow] = eb * inv;
        }
      }
    }
  }
}

// ---------------------------------------------------------------------------
extern "C" void kernel_launch(void* const* d_in, const int* in_sizes, int n_in,
                              void* d_out, int out_size, void* d_ws, size_t ws_size,
                              hipStream_t stream) {
  const float* Q    = (const float*)d_in[0];
  const float* Xf   = (const float*)d_in[1];
  const float* Wv   = (const float*)d_in[2];
  const float* bv   = (const float*)d_in[3];
  const float* Wso  = (const float*)d_in[4];
  const float* bso  = (const float*)d_in[5];
  const float* Waw  = (const float*)d_in[6];
  const float* baw  = (const float*)d_in[7];
  const float* Wtso = (const float*)d_in[8];
  const float* btso = (const float*)d_in[9];
  const float* Wtaw = (const float*)d_in[10];
  const float* btaw = (const float*)d_in[11];
  float* out = (float*)d_out;

  unsigned short* Wt = (unsigned short*)d_ws;               // 512 KB
  float* bcat = (float*)((char*)d_ws + 1024 * 256 * 2);     // 4 KB

  int M = in_sizes[0] / 256;  // 97920

  prep_weights<<<1024, 256, 0, stream>>>(Wv, bv, Wso, bso, Waw, baw,
                                         Wtso, btso, Wtaw, btaw, Wt, bcat);

  dim3 g(4, M / 128);  // remapped in-kernel for XCD L2 panel locality
  gemm_main<<<g, 512, 0, stream>>>(Q, Xf, Wt, bcat, out, M);
}